// Round 4
// baseline (1003.560 us; speedup 1.0000x reference)
//
#include <hip/hip_runtime.h>
#include <cstddef>

typedef _Float16 f16x8 __attribute__((ext_vector_type(8)));
typedef float f32x4 __attribute__((ext_vector_type(4)));

#define B_ 8
#define C_ 1024
#define T_ 8
#define H_ 28
#define W_ 28
#define E_ 512
#define N_ (T_*H_*W_)          // 6272
#define M_ (T_*(H_/2)*(W_/2))  // 1568
#define MP_ 1792               // M padded to 7*256 (contraction-safe: pad cols of P are zeroed)

__device__ __forceinline__ void gld16(const _Float16* g, _Float16* l) {
    __builtin_amdgcn_global_load_lds((const __attribute__((address_space(1))) void*)g,
                                     (__attribute__((address_space(3))) void*)l, 16, 0, 0);
}

// ---------------------------------------------------------------------------
// prep: weights fp32->f16, fold BN + b_out into scale/shift
// ---------------------------------------------------------------------------
__global__ void prep_kernel(const float* __restrict__ wt, const float* __restrict__ wp,
                            const float* __restrict__ wg, const float* __restrict__ wo,
                            const float* __restrict__ b_out,
                            const float* __restrict__ gamma, const float* __restrict__ beta,
                            const float* __restrict__ mean, const float* __restrict__ var,
                            _Float16* __restrict__ wt_h, _Float16* __restrict__ wp_h,
                            _Float16* __restrict__ wg_h, _Float16* __restrict__ wo_h,
                            float* __restrict__ scale, float* __restrict__ shift,
                            int nW, int nC)
{
    int i = blockIdx.x * blockDim.x + threadIdx.x;
    if (i < nW) {
        wt_h[i] = (_Float16)wt[i];
        wp_h[i] = (_Float16)wp[i];
        wg_h[i] = (_Float16)wg[i];
        wo_h[i] = (_Float16)wo[i];
    }
    if (i < nC) {
        float sc = gamma[i] * rsqrtf(var[i] + 1e-5f);
        scale[i] = sc;
        shift[i] = (b_out[i] - mean[i]) * sc + beta[i];
    }
}

// ---------------------------------------------------------------------------
// XT[b][n][c] = (f16) x[b][c][n]
// ---------------------------------------------------------------------------
__global__ void xt_kernel(const float* __restrict__ x, _Float16* __restrict__ XT)
{
    __shared__ float sm[32][33];
    int n0 = blockIdx.x * 32, c0 = blockIdx.y * 32, b = blockIdx.z;
    const float* xb = x + (size_t)b * C_ * N_;
    _Float16* xtb = XT + (size_t)b * N_ * C_;
#pragma unroll
    for (int i = 0; i < 4; i++) {
        int c = c0 + threadIdx.y + i * 8;
        sm[threadIdx.y + i * 8][threadIdx.x] = xb[(size_t)c * N_ + n0 + threadIdx.x];
    }
    __syncthreads();
#pragma unroll
    for (int i = 0; i < 4; i++) {
        int n = n0 + threadIdx.y + i * 8;
        xtb[(size_t)n * C_ + c0 + threadIdx.x] = (_Float16)sm[threadIdx.x][threadIdx.y + i * 8];
    }
}

// ---------------------------------------------------------------------------
// XST[b][m][c] = (f16) maxpool_122(x)[b][c][m], rows m in [M_,MP_) zero-padded
// ---------------------------------------------------------------------------
__global__ void pool_kernel(const float* __restrict__ x, _Float16* __restrict__ XST)
{
    __shared__ float sm[32][33];
    const int H2 = H_ / 2, W2 = W_ / 2, HW = H_ * W_;
    int m0 = blockIdx.x * 32, c0 = blockIdx.y * 32, b = blockIdx.z;
    const float* xb = x + (size_t)b * C_ * T_ * HW;
#pragma unroll
    for (int i = 0; i < 4; i++) {
        int c = c0 + threadIdx.y + i * 8;
        int m = m0 + threadIdx.x;
        float v = 0.f;
        if (m < M_) {
            int t = m / (H2 * W2);
            int r = m - t * (H2 * W2);
            int h2 = r / W2;
            int w2 = r - h2 * W2;
            const float* p = xb + ((size_t)c * T_ + t) * HW + (h2 * 2) * W_ + w2 * 2;
            float v0 = fmaxf(p[0], p[1]);
            float v1 = fmaxf(p[W_], p[W_ + 1]);
            v = fmaxf(v0, v1);
        }
        sm[threadIdx.y + i * 8][threadIdx.x] = v;
    }
    __syncthreads();
#pragma unroll
    for (int i = 0; i < 4; i++) {
        int m = m0 + threadIdx.y + i * 8;
        XST[((size_t)b * MP_ + m) * C_ + c0 + threadIdx.x] = (_Float16)sm[threadIdx.x][threadIdx.y + i * 8];
    }
}

// ---------------------------------------------------------------------------
// in-place softmax over rows of S [rows x MP_] f16 (valid cols [0,M_), pad
// cols [M_,MP_) are overwritten with 0 so the PV contraction over MP_ is exact)
// ---------------------------------------------------------------------------
__global__ void softmax_kernel(_Float16* __restrict__ S, int rows)
{
    int wave = threadIdx.x >> 6, lane = threadIdx.x & 63;
    int row = blockIdx.x * 4 + wave;
    if (row >= rows) return;
    _Float16* s = S + (size_t)row * MP_;
    f16x8 v[4];
    bool val[4];
    float mx = -3.4e38f;
#pragma unroll
    for (int it = 0; it < 4; it++) {
        int base = it * 512 + lane * 8;
        val[it] = (base < M_);
        if (val[it]) {
            v[it] = *(const f16x8*)(s + base);
#pragma unroll
            for (int q = 0; q < 8; q++) mx = fmaxf(mx, (float)v[it][q]);
        }
    }
#pragma unroll
    for (int off = 32; off > 0; off >>= 1) mx = fmaxf(mx, __shfl_xor(mx, off, 64));
    float ev[32];
    float sum = 0.f;
#pragma unroll
    for (int it = 0; it < 4; it++) {
        if (val[it]) {
#pragma unroll
            for (int q = 0; q < 8; q++) {
                float e = __expf((float)v[it][q] - mx);
                ev[it * 8 + q] = e;
                sum += e;
            }
        }
    }
#pragma unroll
    for (int off = 32; off > 0; off >>= 1) sum += __shfl_xor(sum, off, 64);
    float inv = 1.f / sum;
#pragma unroll
    for (int it = 0; it < 4; it++) {
        int base = it * 512 + lane * 8;
        if (val[it]) {
            f16x8 o;
#pragma unroll
            for (int q = 0; q < 8; q++) o[q] = (_Float16)(ev[it * 8 + q] * inv);
            *(f16x8*)(s + base) = o;
        } else if (base < MP_) {
            f16x8 z = {0, 0, 0, 0, 0, 0, 0, 0};
            *(f16x8*)(s + base) = z;
        }
    }
}

// ---------------------------------------------------------------------------
// 256x256 8-phase NT GEMM (T2 swizzle + T3/T4 counted vmcnt + T5 setprio).
// C[m,n] = sum_k A[m,k]*B[n,k] (+bias).  512 thr / 8 waves (2Mx4N), BK=64,
// 2 K-tiles per iteration, LDS 128 KiB double-buffered.
// A rows clamped to Mdim (stores masked); Ndim and K must be 256/128-divisible.
// BIAS: 0 none, 1 per-col, 2 per-row.  Output f16.
// ---------------------------------------------------------------------------
template<int BIAS>
__global__ __launch_bounds__(512, 2)
void gemm8(const _Float16* __restrict__ A, const _Float16* __restrict__ B,
           _Float16* __restrict__ Cout, const float* __restrict__ bias,
           int Mdim, int Ndim, int K,
           long long strideA, long long strideB, long long strideC)
{
    __shared__ alignas(16) _Float16 sA[2][256 * 64];
    __shared__ alignas(16) _Float16 sB[2][256 * 64];

    const int tid = threadIdx.x;
    const int lane = tid & 63;
    const int wave = tid >> 6;      // 0..7
    const int wm = wave >> 2;       // 0..1 (row group of 128)
    const int wn = wave & 3;        // 0..3 (col group of 64)
    const int lane15 = lane & 15;
    const int quad = lane >> 4;

    const int n0 = blockIdx.x * 256;
    const int m0 = blockIdx.y * 256;
    A += (size_t)blockIdx.z * strideA;
    B += (size_t)blockIdx.z * strideB;

    // staging geometry: half-tile = 128 rows x 64 k (16 KiB); 512 thr x 2 loads
    // x 16 B.  chunk id ci = (wave*2+q)*64 + lane -> phys (row=ci>>3, kc=ci&7).
    // swizzle: physical chunk p holds logical chunk p ^ (row&7)  (involution),
    // applied on the per-lane GLOBAL source (LDS dest stays linear, rule #21).
    const int ci = wave * 128 + lane;          // q = 0
    const int row_q0 = ci >> 3;                // 0..127 (q=1 adds 8)
    const int klc = (ci & 7) ^ (row_q0 & 7);   // same for q=0 and q=1

    const _Float16* ap[2][2];                  // [q][half]
    const _Float16* bp[2][2];
#pragma unroll
    for (int q = 0; q < 2; q++)
#pragma unroll
        for (int h = 0; h < 2; h++) {
            int rw = row_q0 + q * 8;
            ap[q][h] = A + (size_t)min(m0 + h * 128 + rw, Mdim - 1) * K + klc * 8;
            bp[q][h] = B + (size_t)min(n0 + h * 128 + rw, Ndim - 1) * K + klc * 8;
        }

    f32x4 acc[8][4];
#pragma unroll
    for (int i = 0; i < 8; i++)
#pragma unroll
        for (int j = 0; j < 4; j++) acc[i][j] = (f32x4){0.f, 0.f, 0.f, 0.f};

    f16x8 af[4][2];        // [rowfrag][kstep] for current qr
    f16x8 bf[2][2][2];     // [qc][colfrag][kstep]

    char* sAc = (char*)sA;
    char* sBc = (char*)sB;

    auto stage_a = [&](int buf, int h, int kt) {
        gld16(ap[0][h] + kt * 64, (_Float16*)(sAc + buf * 32768 + h * 16384 + wave * 2048));
        gld16(ap[1][h] + kt * 64, (_Float16*)(sAc + buf * 32768 + h * 16384 + wave * 2048 + 1024));
    };
    auto stage_b = [&](int buf, int h, int kt) {
        gld16(bp[0][h] + kt * 64, (_Float16*)(sBc + buf * 32768 + h * 16384 + wave * 2048));
        gld16(bp[1][h] + kt * 64, (_Float16*)(sBc + buf * 32768 + h * 16384 + wave * 2048 + 1024));
    };
    auto rd_a = [&](int buf, int qr) {
#pragma unroll
        for (int rf = 0; rf < 4; rf++)
#pragma unroll
            for (int ks = 0; ks < 2; ks++) {
                int row = wm * 128 + qr * 64 + rf * 16 + lane15;
                int c = (ks * 4 + quad) ^ (row & 7);
                af[rf][ks] = *(const f16x8*)(sAc + buf * 32768 + row * 128 + c * 16);
            }
    };
    auto rd_b = [&](int buf, int qc) {
#pragma unroll
        for (int cf = 0; cf < 2; cf++)
#pragma unroll
            for (int ks = 0; ks < 2; ks++) {
                int row = wn * 64 + qc * 32 + cf * 16 + lane15;
                int c = (ks * 4 + quad) ^ (row & 7);
                bf[qc][cf][ks] = *(const f16x8*)(sBc + buf * 32768 + row * 128 + c * 16);
            }
    };
    auto mm = [&](int qr, int qc) {
        __builtin_amdgcn_s_setprio(1);
#pragma unroll
        for (int rf = 0; rf < 4; rf++)
#pragma unroll
            for (int cf = 0; cf < 2; cf++)
#pragma unroll
                for (int ks = 0; ks < 2; ks++)
                    acc[qr * 4 + rf][qc * 2 + cf] = __builtin_amdgcn_mfma_f32_16x16x32_f16(
                        af[rf][ks], bf[qc][cf][ks], acc[qr * 4 + rf][qc * 2 + cf], 0, 0, 0);
        __builtin_amdgcn_s_setprio(0);
    };

#define BAR() __builtin_amdgcn_s_barrier()
#define WAIT_LGKM() do { asm volatile("s_waitcnt lgkmcnt(0)" ::: "memory"); \
                         __builtin_amdgcn_sched_barrier(0); } while (0)
#define WAIT_VM4() asm volatile("s_waitcnt vmcnt(4)" ::: "memory")

    const int nIter = K >> 7;          // K/128 (two 64-K-tiles per iteration)
    const int ktMax = (K >> 6) - 1;

    // prologue: kt0 full (A+B) into buf0; B of kt1 into buf1
    stage_a(0, 0, 0); stage_a(0, 1, 0);
    stage_b(0, 0, 0); stage_b(0, 1, 0);
    stage_b(1, 0, 1); stage_b(1, 1, 1);
    WAIT_VM4();                        // kt0 complete, B-kt1 in flight
    BAR();

    for (int t = 0; t < nIter; t++) {
        const int k1 = 2 * t + 1;
        const int k2 = min(2 * t + 2, ktMax);
        const int k3 = min(2 * t + 3, ktMax);
        // P1: reads buf0 (A qr0 + B qc0), stages A-buf1 h0 (kt k1)
        rd_a(0, 0); rd_b(0, 0);
        stage_a(1, 0, k1);
        BAR(); WAIT_LGKM(); mm(0, 0); BAR();
        // P2: reads B qc1 buf0, stages A-buf1 h1
        rd_b(0, 1);
        stage_a(1, 1, k1);
        BAR(); WAIT_LGKM(); mm(0, 1); BAR();
        // P3: reads A qr1 buf0, stages B-buf0 h0 (kt k2)
        rd_a(0, 1);
        stage_b(0, 0, k2);
        BAR(); WAIT_LGKM(); mm(1, 1); BAR();
        // P4: stages B-buf0 h1; counted vmcnt (A-buf1/B-buf1 complete for P5)
        stage_b(0, 1, k2);
        BAR(); WAIT_LGKM(); mm(1, 0);
        WAIT_VM4();
        BAR();
        // P5: reads buf1 (A qr0 + B qc0), stages A-buf0 h0 (kt k2)
        rd_a(1, 0); rd_b(1, 0);
        stage_a(0, 0, k2);
        BAR(); WAIT_LGKM(); mm(0, 0); BAR();
        // P6
        rd_b(1, 1);
        stage_a(0, 1, k2);
        BAR(); WAIT_LGKM(); mm(0, 1); BAR();
        // P7
        rd_a(1, 1);
        stage_b(1, 0, k3);
        BAR(); WAIT_LGKM(); mm(1, 1); BAR();
        // P8: counted vmcnt (buf0 kt k2 complete for next P1)
        stage_b(1, 1, k3);
        BAR(); WAIT_LGKM(); mm(1, 0);
        WAIT_VM4();
        BAR();
    }
#undef BAR
#undef WAIT_LGKM
#undef WAIT_VM4

    // epilogue: drain staging, then LDS-transpose (alias sA) for vector stores.
    asm volatile("s_waitcnt vmcnt(0)" ::: "memory");
    __syncthreads();
    float* slab = (float*)sAc;                 // 32 x 268 f32 = 34304 B <= 64 KiB
    const size_t cbase = (size_t)blockIdx.z * strideC;
#pragma unroll
    for (int i = 0; i < 8; i++) {              // i = qr*4+rf -> row offset (i>>2)*64+(i&3)*16
        __syncthreads();
#pragma unroll
        for (int cf = 0; cf < 4; cf++) {       // cf = qc*2+colfrag -> col offset (cf>>1)*32+(cf&1)*16
            int col = wn * 64 + (cf >> 1) * 32 + (cf & 1) * 16 + lane15;
            int srb = wm * 16 + quad * 4;
#pragma unroll
            for (int r = 0; r < 4; r++)
                slab[(srb + r) * 268 + col] = acc[i][cf][r];
        }
        __syncthreads();
        int sr = tid & 31, cb = tid >> 5;
        int g = m0 + (sr >> 4) * 128 + (i >> 2) * 64 + (i & 3) * 16 + (sr & 15);
        if (g < Mdim) {
            int gcol = n0 + cb * 16;
            float vv[16];
#pragma unroll
            for (int k4 = 0; k4 < 4; k4++) {
                f32x4 v = *(const f32x4*)&slab[sr * 268 + cb * 16 + k4 * 4];
#pragma unroll
                for (int j = 0; j < 4; j++) vv[k4 * 4 + j] = v[j];
            }
            if (BIAS == 1) {
#pragma unroll
                for (int j = 0; j < 16; j++) vv[j] += bias[gcol + j];
            }
            if (BIAS == 2) {
                float bb = bias[g];
#pragma unroll
                for (int j = 0; j < 16; j++) vv[j] += bb;
            }
            f16x8 o0, o1;
#pragma unroll
            for (int j = 0; j < 8; j++) { o0[j] = (_Float16)vv[j]; o1[j] = (_Float16)vv[8 + j]; }
            _Float16* cp = Cout + cbase + (size_t)g * Ndim + gcol;
            *(f16x8*)cp = o0;
            *(f16x8*)(cp + 8) = o1;
        }
    }
}

// ---------------------------------------------------------------------------
// legacy 128x128 NT GEMM, kept for the fused BN+residual output GEMM
// (memory-bound; N=6272 not 256-divisible).  EPI==2 path only.
// ---------------------------------------------------------------------------
template<int BIAS, int EPI>
__global__ __launch_bounds__(256, 2)
void gemm_nt(const _Float16* __restrict__ A, const _Float16* __restrict__ B,
             void* __restrict__ Cout, const float* __restrict__ bias,
             const float* __restrict__ scale, const float* __restrict__ shift,
             const float* __restrict__ resid,
             int Mdim, int Ndim, int K,
             long long strideA, long long strideB, long long strideC)
{
    __shared__ alignas(16) _Float16 As[128 * 32];
    __shared__ alignas(16) _Float16 Bs[128 * 32];
    __shared__ alignas(16) float eps_[32 * 132];

    const int tid = threadIdx.x;
    const int lane = tid & 63;
    const int wave = tid >> 6;
    const int wm = wave >> 1, wn = wave & 1;
    const int lane15 = lane & 15, quad = lane >> 4;

    const int m0 = blockIdx.y * 128;
    const int n0 = blockIdx.x * 128;
    const int bz = blockIdx.z;
    A += (size_t)bz * strideA;
    B += (size_t)bz * strideB;

    const int c0 = wave * 128 + lane;
    const int c1 = c0 + 64;
    const int ar0 = min(m0 + (c0 >> 2), Mdim - 1);
    const int ar1 = min(m0 + (c1 >> 2), Mdim - 1);
    const int br0 = min(n0 + (c0 >> 2), Ndim - 1);
    const int br1 = min(n0 + (c1 >> 2), Ndim - 1);
    const _Float16* ap0 = A + (size_t)ar0 * K + (c0 & 3) * 8;
    const _Float16* ap1 = A + (size_t)ar1 * K + (c1 & 3) * 8;
    const _Float16* bp0 = B + (size_t)br0 * K + (c0 & 3) * 8;
    const _Float16* bp1 = B + (size_t)br1 * K + (c1 & 3) * 8;
    _Float16* lA0 = As + wave * 1024;
    _Float16* lA1 = As + wave * 1024 + 512;
    _Float16* lB0 = Bs + wave * 1024;
    _Float16* lB1 = Bs + wave * 1024 + 512;

    f32x4 acc[4][4];
#pragma unroll
    for (int i = 0; i < 4; i++)
#pragma unroll
        for (int j = 0; j < 4; j++)
            acc[i][j] = (f32x4){0.f, 0.f, 0.f, 0.f};

    for (int k0 = 0; k0 < K; k0 += 32) {
        __syncthreads();
        gld16(ap0 + k0, lA0);
        gld16(ap1 + k0, lA1);
        gld16(bp0 + k0, lB0);
        gld16(bp1 + k0, lB1);
        __syncthreads();

        f16x8 af[4], bf[4];
#pragma unroll
        for (int i = 0; i < 4; i++)
            af[i] = *(const f16x8*)&As[(wm * 64 + i * 16 + lane15) * 32 + quad * 8];
#pragma unroll
        for (int j = 0; j < 4; j++)
            bf[j] = *(const f16x8*)&Bs[(wn * 64 + j * 16 + lane15) * 32 + quad * 8];
#pragma unroll
        for (int i = 0; i < 4; i++)
#pragma unroll
            for (int j = 0; j < 4; j++)
                acc[i][j] = __builtin_amdgcn_mfma_f32_16x16x32_f16(af[i], bf[j], acc[i][j], 0, 0, 0);
    }

    const size_t cbase = (size_t)bz * strideC;
#pragma unroll
    for (int i = 0; i < 4; i++) {
        __syncthreads();
#pragma unroll
        for (int j = 0; j < 4; j++) {
            int col = wn * 64 + j * 16 + lane15;
#pragma unroll
            for (int r = 0; r < 4; r++)
                eps_[(wm * 16 + quad * 4 + r) * 132 + col] = acc[i][j][r];
        }
        __syncthreads();
        if (EPI == 2) {
            int rg = tid >> 5, cc = tid & 31;
#pragma unroll
            for (int r = 0; r < 4; r++) {
                int lr = rg * 4 + r;
                int grow = m0 + (lr >> 4) * 64 + i * 16 + (lr & 15);
                int gcol = n0 + cc * 4;
                size_t idx = cbase + (size_t)grow * Ndim + gcol;
                f32x4 v = *(const f32x4*)&eps_[lr * 132 + cc * 4];
                f32x4 res = *(const f32x4*)&resid[idx];
                float sc = scale[grow], sh = shift[grow];
                f32x4 o;
#pragma unroll
                for (int q = 0; q < 4; q++) o[q] = v[q] * sc + sh + res[q];
                *(f32x4*)&((float*)Cout)[idx] = o;
            }
        } else {
            int rg = tid >> 4, cc8 = tid & 15;
#pragma unroll
            for (int r2 = 0; r2 < 2; r2++) {
                int lr = rg * 2 + r2;
                int grow = m0 + (lr >> 4) * 64 + i * 16 + (lr & 15);
                int gcol = n0 + cc8 * 8;
                if (grow < Mdim && gcol < Ndim) {
                    f16x8 o;
#pragma unroll
                    for (int q = 0; q < 8; q++) {
                        float v2 = eps_[lr * 132 + cc8 * 8 + q];
                        if (BIAS == 1) v2 += bias[gcol + q];
                        if (BIAS == 2) v2 += bias[grow];
                        o[q] = (_Float16)v2;
                    }
                    *(f16x8*)&((_Float16*)Cout)[cbase + (size_t)grow * Ndim + gcol] = o;
                }
            }
        }
    }
}

// ---------------------------------------------------------------------------
extern "C" void kernel_launch(void* const* d_in, const int* in_sizes, int n_in,
                              void* d_out, int out_size, void* d_ws, size_t ws_size,
                              hipStream_t stream)
{
    const float* x       = (const float*)d_in[0];
    const float* w_theta = (const float*)d_in[1];
    const float* b_theta = (const float*)d_in[2];
    const float* w_phi   = (const float*)d_in[3];
    const float* b_phi   = (const float*)d_in[4];
    const float* w_g     = (const float*)d_in[5];
    const float* b_g     = (const float*)d_in[6];
    const float* w_out   = (const float*)d_in[7];
    const float* b_out   = (const float*)d_in[8];
    const float* gamma   = (const float*)d_in[9];
    const float* beta    = (const float*)d_in[10];
    const float* mean    = (const float*)d_in[11];
    const float* var     = (const float*)d_in[12];
    float* out = (float*)d_out;
    (void)in_sizes; (void)n_in; (void)out_size;

    char* ws = (char*)d_ws;
    size_t off = 0;
    auto alloc = [&](size_t bytes) -> void* {
        off = (off + 255) & ~(size_t)255;
        void* p = ws + off;
        off += bytes;
        return p;
    };

    _Float16* wt_h = (_Float16*)alloc((size_t)E_ * C_ * 2);
    _Float16* wp_h = (_Float16*)alloc((size_t)E_ * C_ * 2);
    _Float16* wg_h = (_Float16*)alloc((size_t)E_ * C_ * 2);
    _Float16* wo_h = (_Float16*)alloc((size_t)C_ * E_ * 2);
    float* scale   = (float*)alloc((size_t)C_ * 4);
    float* shift   = (float*)alloc((size_t)C_ * 4);
    _Float16* XT   = (_Float16*)alloc((size_t)B_ * N_ * C_ * 2);
    _Float16* XST  = (_Float16*)alloc((size_t)B_ * MP_ * C_ * 2);
    _Float16* Th   = (_Float16*)alloc((size_t)B_ * N_ * E_ * 2);
    _Float16* Ph   = (_Float16*)alloc((size_t)B_ * MP_ * E_ * 2);
    _Float16* Gb   = (_Float16*)alloc((size_t)B_ * E_ * MP_ * 2);
    _Float16* Yt   = (_Float16*)alloc((size_t)B_ * N_ * E_ * 2);

    size_t sz_s_all = (size_t)B_ * N_ * MP_ * 2;
    bool batched = ws_size > off + sz_s_all + 65536;
    _Float16* Sall = (_Float16*)alloc(batched ? sz_s_all : (size_t)N_ * MP_ * 2);

    prep_kernel<<<dim3((E_ * C_) / 256), dim3(256), 0, stream>>>(
        w_theta, w_phi, w_g, w_out, b_out, gamma, beta, mean, var,
        wt_h, wp_h, wg_h, wo_h, scale, shift, E_ * C_, C_);

    xt_kernel<<<dim3(N_ / 32, C_ / 32, B_), dim3(32, 8), 0, stream>>>(x, XT);
    pool_kernel<<<dim3(MP_ / 32, C_ / 32, B_), dim3(32, 8), 0, stream>>>(x, XST);

    // ThetaT [N,E] = XT[N,C] * wt^T  (rows clamped/masked: 25 tiles of 256)
    gemm8<1><<<dim3(E_ / 256, (N_ + 255) / 256, B_), dim3(512), 0, stream>>>(
        XT, wt_h, Th, b_theta, N_, E_, C_,
        (long long)N_ * C_, 0, (long long)N_ * E_);

    // PhiT [MP,E] (pad rows = bias, finite; never used past softmax masking)
    gemm8<1><<<dim3(E_ / 256, MP_ / 256, B_), dim3(512), 0, stream>>>(
        XST, wp_h, Ph, b_phi, MP_, E_, C_,
        (long long)MP_ * C_, 0, (long long)MP_ * E_);

    // G [E,MP], bias per-row (pad cols finite; multiplied by zeroed P cols)
    gemm8<2><<<dim3(MP_ / 256, E_ / 256, B_), dim3(512), 0, stream>>>(
        wg_h, XST, Gb, b_g, E_, MP_, C_,
        0, (long long)MP_ * C_, (long long)E_ * MP_);

    const int nbz = batched ? B_ : 1;
    for (int b0 = 0; b0 < B_; b0 += nbz) {
        // S [N,MP] f16 = ThetaT * PhiT^T
        gemm8<0><<<dim3(MP_ / 256, (N_ + 255) / 256, nbz), dim3(512), 0, stream>>>(
            Th + (size_t)b0 * N_ * E_, Ph + (size_t)b0 * MP_ * E_, Sall, nullptr,
            N_, MP_, E_,
            (long long)N_ * E_, (long long)MP_ * E_, (long long)N_ * MP_);

        softmax_kernel<<<dim3((nbz * N_) / 4), dim3(256), 0, stream>>>(Sall, nbz * N_);

        // YT [N,E] = P[N,MP] * G[E,MP]^T   (pad cols of P are zero)
        gemm8<0><<<dim3(E_ / 256, (N_ + 255) / 256, nbz), dim3(512), 0, stream>>>(
            Sall, Gb + (size_t)b0 * E_ * MP_, Yt + (size_t)b0 * N_ * E_, nullptr,
            N_, E_, MP_,
            (long long)N_ * MP_, (long long)E_ * MP_, (long long)N_ * E_);
    }

    // out [B,C,N] = BN(w_out*Y + b_out) + x   (memory-bound, legacy kernel)
    gemm_nt<0, 2><<<dim3(N_ / 128, C_ / 128, B_), dim3(256), 0, stream>>>(
        wo_h, Yt, out, nullptr, scale, shift, x,
        C_, N_, E_, 0, (long long)N_ * E_, (long long)C_ * N_);
}